// Round 6
// baseline (112.152 us; speedup 1.0000x reference)
//
#include <hip/hip_runtime.h>
#include <hip/hip_bf16.h>

#define B_ 256
#define N_ 784
#define E_ 6272
#define C_ 32
#define H_ 512
#define NK 25088            // N_*C_
#define BC 8192             // B_*C_ (h1 node stride)
#define S_SPLIT 28
#define FC1_KSTEPS 28       // 28 * 32 * 28 = 25088

typedef __attribute__((ext_vector_type(8))) short short8;
typedef __attribute__((ext_vector_type(4))) float f32x4;

__device__ __forceinline__ float elu1(float v) {
  return v > 0.f ? v : (__expf(v) - 1.f);
}

__device__ __forceinline__ unsigned short bf16b(float v) {
  __hip_bfloat16 h = __float2bfloat16(v);
  return *reinterpret_cast<unsigned short*>(&h);
}

__device__ __forceinline__ unsigned int pk2(float lo, float hi) {
  return (unsigned int)bf16b(lo) | ((unsigned int)bf16b(hi) << 16);
}

__device__ __forceinline__ void acc2(unsigned u, float val, float& a0, float& a1) {
  float lo = __uint_as_float(u << 16);
  float hi = __uint_as_float(u & 0xffff0000u);
  a0 = fmaf(val, lo, a0);
  a1 = fmaf(val, hi, a1);
}

// ---------------- K0: block 0 builds CSR; blocks 1.. transpose x ----------------
__global__ __launch_bounds__(1024) void k_prep(
    const int* __restrict__ erow, const int* __restrict__ ecol,
    const float* __restrict__ eval, const float* __restrict__ x,
    int* __restrict__ row_ptr, int* __restrict__ col_s, float* __restrict__ val_s,
    float* __restrict__ xT) {
  const int t = threadIdx.x;
  if (blockIdx.x == 0) {
    __shared__ int cnt[N_];
    __shared__ int off[N_];
    __shared__ int bufA[1024];
    __shared__ int bufB[1024];
    if (t < N_) cnt[t] = 0;
    __syncthreads();
    for (int e = t; e < E_; e += 1024) atomicAdd(&cnt[erow[e]], 1);
    __syncthreads();
    bufA[t] = (t < N_) ? cnt[t] : 0;
    __syncthreads();
    int* src = bufA; int* dst = bufB;
    for (int d = 1; d < 1024; d <<= 1) {
      int v = src[t];
      if (t >= d) v += src[t - d];
      dst[t] = v;
      __syncthreads();
      int* tmp = src; src = dst; dst = tmp;
    }
    if (t < N_) {
      int ex = src[t] - cnt[t];
      off[t] = ex;
      row_ptr[t] = ex;
    }
    if (t == 0) row_ptr[N_] = E_;
    __syncthreads();
    for (int e = t; e < E_; e += 1024) {
      int r = erow[e];
      int p = atomicAdd(&off[r], 1);
      col_s[p] = ecol[e];
      val_s[p] = eval[e];
    }
  } else {
    __shared__ float tile[32][33];
    int bid = blockIdx.x - 1;
    int n0 = (bid % 25) * 32, b0 = (bid / 25) * 32;
    int ni = t & 31, bi = t >> 5;
    int n = n0 + ni;
    if (n < N_) tile[ni][bi] = x[(b0 + bi) * N_ + n];
    __syncthreads();
    int nj = t >> 5, bj = t & 31;
    int nw = n0 + nj;
    if (nw < N_) xT[nw * B_ + b0 + bj] = tile[nj][bj];
  }
}

// ---------------- K1: spmm1 + W1 + elu -> h1[n][b*32+c] (bf16, node-major) ----
__global__ __launch_bounds__(256) void k_gc1(
    const float* __restrict__ xT, const int* __restrict__ row_ptr,
    const int* __restrict__ col_s, const float* __restrict__ val_s,
    const float* __restrict__ W1, const float* __restrict__ b1,
    __hip_bfloat16* __restrict__ h1) {
  __shared__ int lc[64];
  __shared__ float lv[64];
  int n = blockIdx.x, t = threadIdx.x;
  int e0 = row_ptr[n], deg = row_ptr[n + 1] - e0;
  float agg = 0.f;
  for (int base = 0; base < deg; base += 64) {
    int m = min(64, deg - base);
    __syncthreads();
    if (t < m) { lc[t] = col_s[e0 + base + t]; lv[t] = val_s[e0 + base + t]; }
    __syncthreads();
    for (int e = 0; e < m; ++e)
      agg = fmaf(lv[e], xT[lc[e] * B_ + t], agg);
  }
  union { unsigned int u[16]; uint4 v[4]; } ob;
#pragma unroll
  for (int c = 0; c < C_; c += 2) {
    float o0 = elu1(fmaf(agg, W1[c], b1[c]));
    float o1 = elu1(fmaf(agg, W1[c + 1], b1[c + 1]));
    ob.u[c >> 1] = pk2(o0, o1);
  }
  uint4* dst = reinterpret_cast<uint4*>(h1 + (size_t)n * BC + t * C_);
#pragma unroll
  for (int j = 0; j < 4; ++j) dst[j] = ob.v[j];
}

// ---------------- K2: spmm2 (wide gather, 2-edge pipelined) + W2 + elu -> flat ----
__global__ __launch_bounds__(256) void k_gc2(
    const __hip_bfloat16* __restrict__ h1, const int* __restrict__ row_ptr,
    const int* __restrict__ col_s, const float* __restrict__ val_s,
    const float* __restrict__ W2, const float* __restrict__ b2,
    __hip_bfloat16* __restrict__ flat) {
  __shared__ int lc[64];
  __shared__ float lv[64];
  int n = blockIdx.x, t = threadIdx.x;
  int e0 = row_ptr[n], deg = row_ptr[n + 1] - e0;
  float acc[C_];
#pragma unroll
  for (int c = 0; c < C_; ++c) acc[c] = 0.f;

#define ACC16(v0, v1, v2, v3, val) do {                                       \
    acc2(v0.x, val, acc[0], acc[1]);  acc2(v0.y, val, acc[2], acc[3]);        \
    acc2(v0.z, val, acc[4], acc[5]);  acc2(v0.w, val, acc[6], acc[7]);        \
    acc2(v1.x, val, acc[8], acc[9]);  acc2(v1.y, val, acc[10], acc[11]);      \
    acc2(v1.z, val, acc[12], acc[13]); acc2(v1.w, val, acc[14], acc[15]);     \
    acc2(v2.x, val, acc[16], acc[17]); acc2(v2.y, val, acc[18], acc[19]);     \
    acc2(v2.z, val, acc[20], acc[21]); acc2(v2.w, val, acc[22], acc[23]);     \
    acc2(v3.x, val, acc[24], acc[25]); acc2(v3.y, val, acc[26], acc[27]);     \
    acc2(v3.z, val, acc[28], acc[29]); acc2(v3.w, val, acc[30], acc[31]);     \
  } while (0)

  for (int base = 0; base < deg; base += 64) {
    int m = min(64, deg - base);
    __syncthreads();
    if (t < m) { lc[t] = col_s[e0 + base + t]; lv[t] = val_s[e0 + base + t]; }
    __syncthreads();
    int e = 0;
    for (; e + 2 <= m; e += 2) {
      float val0 = lv[e], val1 = lv[e + 1];
      const uint4* hp0 = reinterpret_cast<const uint4*>(
          h1 + (size_t)lc[e] * BC + t * C_);
      const uint4* hp1 = reinterpret_cast<const uint4*>(
          h1 + (size_t)lc[e + 1] * BC + t * C_);
      uint4 v0 = hp0[0], v1 = hp0[1], v2 = hp0[2], v3 = hp0[3];
      uint4 w0 = hp1[0], w1 = hp1[1], w2 = hp1[2], w3 = hp1[3];
      ACC16(v0, v1, v2, v3, val0);
      ACC16(w0, w1, w2, w3, val1);
    }
    if (e < m) {
      float val0 = lv[e];
      const uint4* hp0 = reinterpret_cast<const uint4*>(
          h1 + (size_t)lc[e] * BC + t * C_);
      uint4 v0 = hp0[0], v1 = hp0[1], v2 = hp0[2], v3 = hp0[3];
      ACC16(v0, v1, v2, v3, val0);
    }
  }
#undef ACC16

  union { unsigned int u[16]; uint4 v[4]; } ob;
#pragma unroll
  for (int c2 = 0; c2 < C_; c2 += 2) {
    float o0 = b2[c2], o1 = b2[c2 + 1];
#pragma unroll
    for (int c = 0; c < C_; ++c) {
      o0 = fmaf(acc[c], W2[c * C_ + c2], o0);
      o1 = fmaf(acc[c], W2[c * C_ + c2 + 1], o1);
    }
    ob.u[c2 >> 1] = pk2(elu1(o0), elu1(o1));
  }
  uint4* dst = reinterpret_cast<uint4*>(flat + (size_t)t * NK + n * C_);
#pragma unroll
  for (int j = 0; j < 4; ++j) dst[j] = ob.v[j];
}

// ---------------- K3: fc1 split-K MFMA GEMM -> partial[28][256][512] ----------------
// BM=128, BN=64, 256 threads (4 waves, 2m x 2n; wave tile 64x32). Grid = 16*28.
// Deep pipeline: 4 register stages, issue-distance 3 K-steps, fully unrolled.
// Raw s_barrier + lgkmcnt(0) only -- vmcnt is NEVER drained in the loop; the
// compiler's per-register counted vmcnt waits keep 3 steps of loads in flight.
__global__ __launch_bounds__(256, 2) void k_fc1(
    const __hip_bfloat16* __restrict__ flat, const float* __restrict__ Wf1,
    float* __restrict__ partial) {
  __shared__ unsigned short Alds[2][128][40];   // [m][k], 80B rows
  __shared__ unsigned short Blds[2][64][40];    // [n][k]
  int bid = blockIdx.x;
  int s = bid >> 4, r16 = bid & 15;
  int m0 = (r16 & 1) * 128;
  int n0 = (r16 >> 1) * 64;
  int k0 = s * (FC1_KSTEPS * 32);
  int tid = threadIdx.x;
  int w = tid >> 6, l = tid & 63;
  int r = l & 15, g = l >> 4;
  int wm = (w & 1) * 64;
  int wn = (w >> 1) * 32;
  int am = tid >> 1, ah = (tid & 1) * 16;   // A: row am, 16B half ah
  int bn = tid & 63, boct = tid >> 6;       // B: col bn, k-octet boct

  f32x4 acc[4][2];
#pragma unroll
  for (int i = 0; i < 4; ++i)
#pragma unroll
    for (int j = 0; j < 2; ++j) acc[i][j] = (f32x4){0.f, 0.f, 0.f, 0.f};

  int4 aA[4], aB[4];      // A stage: 2 x int4 per step
  float bF[4][8];         // B stage: 8 f32 per step

#define GLOAD_A(step, v0, v1) do {                                            \
    const int4* _p = reinterpret_cast<const int4*>(                           \
        flat + (size_t)(m0 + am) * NK + k0 + (step) * 32 + ah);               \
    v0 = _p[0]; v1 = _p[1];                                                   \
  } while (0)
#define GLOAD_B(step, f) do {                                                 \
    const float* _b = Wf1 + (size_t)(k0 + (step) * 32 + boct * 8) * H_        \
                      + n0 + bn;                                              \
    _Pragma("unroll")                                                         \
    for (int i = 0; i < 8; ++i) f[i] = _b[i * H_];                            \
  } while (0)
#define WRITE_LDS(buf, v0, v1, f) do {                                        \
    int4* _ad = reinterpret_cast<int4*>(&Alds[buf][am][ah]);                  \
    _ad[0] = v0; _ad[1] = v1;                                                 \
    uint4 _bu;                                                                \
    _bu.x = pk2(f[0], f[1]); _bu.y = pk2(f[2], f[3]);                         \
    _bu.z = pk2(f[4], f[5]); _bu.w = pk2(f[6], f[7]);                         \
    *reinterpret_cast<uint4*>(&Blds[buf][bn][boct * 8]) = _bu;                \
  } while (0)
#define MFMA_STEP(buf) do {                                                   \
    short8 _a[4];                                                             \
    _Pragma("unroll")                                                         \
    for (int fm = 0; fm < 4; ++fm)                                            \
      _a[fm] = *reinterpret_cast<const short8*>(&Alds[buf][wm + fm * 16 + r][g * 8]); \
    _Pragma("unroll")                                                         \
    for (int fn = 0; fn < 2; ++fn) {                                          \
      short8 _bb = *reinterpret_cast<const short8*>(&Blds[buf][wn + fn * 16 + r][g * 8]); \
      _Pragma("unroll")                                                       \
      for (int fm = 0; fm < 4; ++fm)                                          \
        acc[fm][fn] = __builtin_amdgcn_mfma_f32_16x16x32_bf16(_a[fm], _bb, acc[fm][fn], 0, 0, 0); \
    }                                                                         \
  } while (0)
#define BARRIER() do {                                                        \
    asm volatile("s_waitcnt lgkmcnt(0)" ::: "memory");                        \
    __builtin_amdgcn_s_barrier();                                             \
  } while (0)
#define STEP(i) do {                                                          \
    if ((i) + 4 < FC1_KSTEPS) {                                               \
      GLOAD_A((i) + 4, aA[((i) + 4) & 3], aB[((i) + 4) & 3]);                 \
      GLOAD_B((i) + 4, bF[((i) + 4) & 3]);                                    \
    }                                                                         \
    if ((i) + 1 < FC1_KSTEPS)                                                 \
      WRITE_LDS(((i) + 1) & 1, aA[((i) + 1) & 3], aB[((i) + 1) & 3],          \
                bF[((i) + 1) & 3]);                                           \
    MFMA_STEP((i) & 1);                                                       \
    BARRIER();                                                                \
  } while (0)

  // Prologue: issue steps 0..3, stage step 0 into buf0.
  GLOAD_A(0, aA[0], aB[0]); GLOAD_B(0, bF[0]);
  GLOAD_A(1, aA[1], aB[1]); GLOAD_B(1, bF[1]);
  GLOAD_A(2, aA[2], aB[2]); GLOAD_B(2, bF[2]);
  GLOAD_A(3, aA[3], aB[3]); GLOAD_B(3, bF[3]);
  WRITE_LDS(0, aA[0], aB[0], bF[0]);
  BARRIER();

  STEP(0);  STEP(1);  STEP(2);  STEP(3);  STEP(4);  STEP(5);  STEP(6);
  STEP(7);  STEP(8);  STEP(9);  STEP(10); STEP(11); STEP(12); STEP(13);
  STEP(14); STEP(15); STEP(16); STEP(17); STEP(18); STEP(19); STEP(20);
  STEP(21); STEP(22); STEP(23); STEP(24); STEP(25); STEP(26); STEP(27);

#undef GLOAD_A
#undef GLOAD_B
#undef WRITE_LDS
#undef MFMA_STEP
#undef BARRIER
#undef STEP

  // D layout: col = lane&15 (=r), row = g*4 + q
  float* p = partial + (size_t)s * (256 * 512);
#pragma unroll
  for (int fm = 0; fm < 4; ++fm)
#pragma unroll
    for (int fn = 0; fn < 2; ++fn)
#pragma unroll
      for (int q = 0; q < 4; ++q) {
        int m = m0 + wm + fm * 16 + g * 4 + q;
        int n = n0 + wn + fn * 16 + r;
        p[m * 512 + n] = acc[fm][fn][q];
      }
}

// ---------------- K4: reduce partials + bias + relu + fc2 + softmax ----------------
__global__ __launch_bounds__(512) void k_head(
    const float* __restrict__ partial, const float* __restrict__ bf1,
    const float* __restrict__ Wf2, const float* __restrict__ bf2,
    float* __restrict__ out) {
  __shared__ float red[8][12];
  int b = blockIdx.x;
  int t = threadIdx.x;
  float v = bf1[t];
#pragma unroll
  for (int s = 0; s < S_SPLIT; ++s)
    v += partial[(size_t)s * (256 * 512) + b * 512 + t];
  v = fmaxf(v, 0.f);
  float pacc[10];
#pragma unroll
  for (int j = 0; j < 10; ++j) pacc[j] = v * Wf2[t * 10 + j];
#pragma unroll
  for (int j = 0; j < 10; ++j)
#pragma unroll
    for (int d = 32; d > 0; d >>= 1)
      pacc[j] += __shfl_down(pacc[j], d);
  int wv = t >> 6, ln = t & 63;
  if (ln == 0) {
#pragma unroll
    for (int j = 0; j < 10; ++j) red[wv][j] = pacc[j];
  }
  __syncthreads();
  if (t == 0) {
    float lg[10];
    float m = -1e30f;
#pragma unroll
    for (int j = 0; j < 10; ++j) {
      float z = bf2[j];
#pragma unroll
      for (int wq = 0; wq < 8; ++wq) z += red[wq][j];
      lg[j] = z;
      m = fmaxf(m, z);
    }
    float sum = 0.f;
#pragma unroll
    for (int j = 0; j < 10; ++j) { lg[j] = __expf(lg[j] - m); sum += lg[j]; }
    float inv = 1.f / sum;
#pragma unroll
    for (int j = 0; j < 10; ++j) out[b * 10 + j] = lg[j] * inv;
  }
}

extern "C" void kernel_launch(void* const* d_in, const int* in_sizes, int n_in,
                              void* d_out, int out_size, void* d_ws, size_t ws_size,
                              hipStream_t stream) {
  const float* x    = (const float*)d_in[0];
  const int*   erow = (const int*)d_in[1];
  const int*   ecol = (const int*)d_in[2];
  const float* ev   = (const float*)d_in[3];
  const float* W1   = (const float*)d_in[4];
  const float* b1   = (const float*)d_in[5];
  const float* W2   = (const float*)d_in[6];
  const float* b2   = (const float*)d_in[7];
  const float* Wf1  = (const float*)d_in[8];
  const float* bf1  = (const float*)d_in[9];
  const float* Wf2  = (const float*)d_in[10];
  const float* bf2  = (const float*)d_in[11];
  float* out = (float*)d_out;

  const size_t partial_bytes = (size_t)S_SPLIT * 256 * 512 * 4;   // 14,680,064
  const size_t flat_bytes    = (size_t)B_ * NK * 2;               // 12,845,056

  // ws layout:
  //   [0, 0.80M)         xT f32             (dead after gc1)
  //   [0.80M, 13.65M)    h1 bf16 node-major (dead after gc2)
  //   [0, 14.68M)        partial            (fc1 writes after h1/xT dead)
  //   [14.68M, 27.53M)   flat bf16
  //   tail               CSR (row_ptr, col_s, val_s)
  char* ws = (char*)d_ws;
  float* partial = (float*)ws;
  float* xT = (float*)ws;
  __hip_bfloat16* h1 = (__hip_bfloat16*)(ws + 802816);
  __hip_bfloat16* flat = (__hip_bfloat16*)(ws + partial_bytes);
  char* tail = ws + partial_bytes + flat_bytes;
  int*   row_ptr = (int*)tail;
  int*   col_s   = (int*)(tail + 3152);
  float* val_s   = (float*)(tail + 3152 + E_ * 4);

  hipLaunchKernelGGL(k_prep, dim3(1 + 25 * 8), dim3(1024), 0, stream,
                     erow, ecol, ev, x, row_ptr, col_s, val_s, xT);
  hipLaunchKernelGGL(k_gc1, dim3(N_), dim3(256), 0, stream,
                     xT, row_ptr, col_s, val_s, W1, b1, h1);
  hipLaunchKernelGGL(k_gc2, dim3(N_), dim3(256), 0, stream,
                     h1, row_ptr, col_s, val_s, W2, b2, flat);
  hipLaunchKernelGGL(k_fc1, dim3(16 * S_SPLIT), dim3(256), 0, stream,
                     flat, Wf1, partial);
  hipLaunchKernelGGL(k_head, dim3(B_), dim3(512), 0, stream,
                     partial, bf1, Wf2, bf2, out);
}

// Round 7
// 99.385 us; speedup vs baseline: 1.1285x; 1.1285x over previous
//
#include <hip/hip_runtime.h>
#include <hip/hip_bf16.h>

#define B_ 256
#define N_ 784
#define E_ 6272
#define C_ 32
#define H_ 512
#define NK 25088            // N_*C_
#define BC 8192             // B_*C_ (h1 node stride)
#define S_SPLIT 28
#define FC1_KSTEPS 28       // 28 steps * 32 k * 28 s = 25088

typedef __attribute__((ext_vector_type(8))) short short8;
typedef __attribute__((ext_vector_type(4))) float f32x4;

__device__ __forceinline__ float elu1(float v) {
  return v > 0.f ? v : (__expf(v) - 1.f);
}

__device__ __forceinline__ unsigned short bf16b(float v) {
  __hip_bfloat16 h = __float2bfloat16(v);
  return *reinterpret_cast<unsigned short*>(&h);
}

__device__ __forceinline__ unsigned int pk2(float lo, float hi) {
  return (unsigned int)bf16b(lo) | ((unsigned int)bf16b(hi) << 16);
}

__device__ __forceinline__ void acc2(unsigned u, float val, float& a0, float& a1) {
  float lo = __uint_as_float(u << 16);
  float hi = __uint_as_float(u & 0xffff0000u);
  a0 = fmaf(val, lo, a0);
  a1 = fmaf(val, hi, a1);
}

// ---------------- K0: block 0 builds CSR; blocks 1.. transpose x ----------------
__global__ __launch_bounds__(1024) void k_prep(
    const int* __restrict__ erow, const int* __restrict__ ecol,
    const float* __restrict__ eval, const float* __restrict__ x,
    int* __restrict__ row_ptr, int* __restrict__ col_s, float* __restrict__ val_s,
    float* __restrict__ xT) {
  const int t = threadIdx.x;
  if (blockIdx.x == 0) {
    __shared__ int cnt[N_];
    __shared__ int off[N_];
    __shared__ int bufA[1024];
    __shared__ int bufB[1024];
    if (t < N_) cnt[t] = 0;
    __syncthreads();
    for (int e = t; e < E_; e += 1024) atomicAdd(&cnt[erow[e]], 1);
    __syncthreads();
    bufA[t] = (t < N_) ? cnt[t] : 0;
    __syncthreads();
    int* src = bufA; int* dst = bufB;
    for (int d = 1; d < 1024; d <<= 1) {
      int v = src[t];
      if (t >= d) v += src[t - d];
      dst[t] = v;
      __syncthreads();
      int* tmp = src; src = dst; dst = tmp;
    }
    if (t < N_) {
      int ex = src[t] - cnt[t];
      off[t] = ex;
      row_ptr[t] = ex;
    }
    if (t == 0) row_ptr[N_] = E_;
    __syncthreads();
    for (int e = t; e < E_; e += 1024) {
      int r = erow[e];
      int p = atomicAdd(&off[r], 1);
      col_s[p] = ecol[e];
      val_s[p] = eval[e];
    }
  } else {
    __shared__ float tile[32][33];
    int bid = blockIdx.x - 1;
    int n0 = (bid % 25) * 32, b0 = (bid / 25) * 32;
    int ni = t & 31, bi = t >> 5;
    int n = n0 + ni;
    if (n < N_) tile[ni][bi] = x[(b0 + bi) * N_ + n];
    __syncthreads();
    int nj = t >> 5, bj = t & 31;
    int nw = n0 + nj;
    if (nw < N_) xT[nw * B_ + b0 + bj] = tile[nj][bj];
  }
}

// ---------------- K1: spmm1 + W1 + elu -> h1[n][b*32+c] (bf16, node-major) ----
__global__ __launch_bounds__(256) void k_gc1(
    const float* __restrict__ xT, const int* __restrict__ row_ptr,
    const int* __restrict__ col_s, const float* __restrict__ val_s,
    const float* __restrict__ W1, const float* __restrict__ b1,
    __hip_bfloat16* __restrict__ h1) {
  __shared__ int lc[64];
  __shared__ float lv[64];
  int n = blockIdx.x, t = threadIdx.x;
  int e0 = row_ptr[n], deg = row_ptr[n + 1] - e0;
  float agg = 0.f;
  for (int base = 0; base < deg; base += 64) {
    int m = min(64, deg - base);
    __syncthreads();
    if (t < m) { lc[t] = col_s[e0 + base + t]; lv[t] = val_s[e0 + base + t]; }
    __syncthreads();
    for (int e = 0; e < m; ++e)
      agg = fmaf(lv[e], xT[lc[e] * B_ + t], agg);
  }
  union { unsigned int u[16]; uint4 v[4]; } ob;
#pragma unroll
  for (int c = 0; c < C_; c += 2) {
    float o0 = elu1(fmaf(agg, W1[c], b1[c]));
    float o1 = elu1(fmaf(agg, W1[c + 1], b1[c + 1]));
    ob.u[c >> 1] = pk2(o0, o1);
  }
  uint4* dst = reinterpret_cast<uint4*>(h1 + (size_t)n * BC + t * C_);
#pragma unroll
  for (int j = 0; j < 4; ++j) dst[j] = ob.v[j];
}

// ---------------- K2: spmm2 (wide gather, 2-edge pipelined) + W2 + elu -> flat ----
__global__ __launch_bounds__(256) void k_gc2(
    const __hip_bfloat16* __restrict__ h1, const int* __restrict__ row_ptr,
    const int* __restrict__ col_s, const float* __restrict__ val_s,
    const float* __restrict__ W2, const float* __restrict__ b2,
    __hip_bfloat16* __restrict__ flat) {
  __shared__ int lc[64];
  __shared__ float lv[64];
  int n = blockIdx.x, t = threadIdx.x;
  int e0 = row_ptr[n], deg = row_ptr[n + 1] - e0;
  float acc[C_];
#pragma unroll
  for (int c = 0; c < C_; ++c) acc[c] = 0.f;

#define ACC16(v0, v1, v2, v3, val) do {                                       \
    acc2(v0.x, val, acc[0], acc[1]);  acc2(v0.y, val, acc[2], acc[3]);        \
    acc2(v0.z, val, acc[4], acc[5]);  acc2(v0.w, val, acc[6], acc[7]);        \
    acc2(v1.x, val, acc[8], acc[9]);  acc2(v1.y, val, acc[10], acc[11]);      \
    acc2(v1.z, val, acc[12], acc[13]); acc2(v1.w, val, acc[14], acc[15]);     \
    acc2(v2.x, val, acc[16], acc[17]); acc2(v2.y, val, acc[18], acc[19]);     \
    acc2(v2.z, val, acc[20], acc[21]); acc2(v2.w, val, acc[22], acc[23]);     \
    acc2(v3.x, val, acc[24], acc[25]); acc2(v3.y, val, acc[26], acc[27]);     \
    acc2(v3.z, val, acc[28], acc[29]); acc2(v3.w, val, acc[30], acc[31]);     \
  } while (0)

  for (int base = 0; base < deg; base += 64) {
    int m = min(64, deg - base);
    __syncthreads();
    if (t < m) { lc[t] = col_s[e0 + base + t]; lv[t] = val_s[e0 + base + t]; }
    __syncthreads();
    int e = 0;
    for (; e + 2 <= m; e += 2) {
      float val0 = lv[e], val1 = lv[e + 1];
      const uint4* hp0 = reinterpret_cast<const uint4*>(
          h1 + (size_t)lc[e] * BC + t * C_);
      const uint4* hp1 = reinterpret_cast<const uint4*>(
          h1 + (size_t)lc[e + 1] * BC + t * C_);
      uint4 v0 = hp0[0], v1 = hp0[1], v2 = hp0[2], v3 = hp0[3];
      uint4 w0 = hp1[0], w1 = hp1[1], w2 = hp1[2], w3 = hp1[3];
      ACC16(v0, v1, v2, v3, val0);
      ACC16(w0, w1, w2, w3, val1);
    }
    if (e < m) {
      float val0 = lv[e];
      const uint4* hp0 = reinterpret_cast<const uint4*>(
          h1 + (size_t)lc[e] * BC + t * C_);
      uint4 v0 = hp0[0], v1 = hp0[1], v2 = hp0[2], v3 = hp0[3];
      ACC16(v0, v1, v2, v3, val0);
    }
  }
#undef ACC16

  union { unsigned int u[16]; uint4 v[4]; } ob;
#pragma unroll
  for (int c2 = 0; c2 < C_; c2 += 2) {
    float o0 = b2[c2], o1 = b2[c2 + 1];
#pragma unroll
    for (int c = 0; c < C_; ++c) {
      o0 = fmaf(acc[c], W2[c * C_ + c2], o0);
      o1 = fmaf(acc[c], W2[c * C_ + c2 + 1], o1);
    }
    ob.u[c2 >> 1] = pk2(elu1(o0), elu1(o1));
  }
  uint4* dst = reinterpret_cast<uint4*>(flat + (size_t)t * NK + n * C_);
#pragma unroll
  for (int j = 0; j < 4; ++j) dst[j] = ob.v[j];
}

// ---------------- K3: fc1 split-K MFMA GEMM, NO LDS / NO BARRIERS ----------------
// BM=256 (full M), BN=64, k-chunk 896. grid = 28 s * 8 nt = 224 blocks,
// 512 threads = 8 waves (4m x 2n), wave tile 64m x 32n.
// Each wave loads its A and B fragments DIRECTLY from global in MFMA layout:
//   A: 16B contiguous per lane (flat is L3-resident; re-read 8x = 103 MB L3)
//   B: 8 strided f32 per fragment, cvt to bf16 in-register (Wf1 read once: 51.4 MB)
// 2-deep named-register pipeline (X/Y), zero synchronization.
__global__ __launch_bounds__(512) void k_fc1(
    const __hip_bfloat16* __restrict__ flat, const float* __restrict__ Wf1,
    float* __restrict__ partial) {
  int bid = blockIdx.x;
  int s = bid >> 3, nt = bid & 7;
  int n0 = nt * 64;
  int k0 = s * (FC1_KSTEPS * 32);
  int tid = threadIdx.x;
  int w = tid >> 6, l = tid & 63;
  int r = l & 15, g = l >> 4;
  int wm = (w & 3) * 64;       // 4 m-waves
  int wn = (w >> 2) * 32;      // 2 n-waves
  int col = n0 + wn + r;       // this lane's B column (fn adds +16)

  // Per-fm A row base pointers (lane-fixed); step adds 64B (32 bf16).
  const short8* a_base0 = reinterpret_cast<const short8*>(
      flat + (size_t)(wm + 0 * 16 + r) * NK + k0 + g * 8);
  const short8* a_base1 = reinterpret_cast<const short8*>(
      flat + (size_t)(wm + 1 * 16 + r) * NK + k0 + g * 8);
  const short8* a_base2 = reinterpret_cast<const short8*>(
      flat + (size_t)(wm + 2 * 16 + r) * NK + k0 + g * 8);
  const short8* a_base3 = reinterpret_cast<const short8*>(
      flat + (size_t)(wm + 3 * 16 + r) * NK + k0 + g * 8);
  // B base (lane-fixed): k = k0 + g*8, advance by 32*H_ per step; i advances H_.
  const float* b_base = Wf1 + (size_t)(k0 + g * 8) * H_ + col;

  f32x4 acc[4][2];
#pragma unroll
  for (int i = 0; i < 4; ++i)
#pragma unroll
    for (int j = 0; j < 2; ++j) acc[i][j] = (f32x4){0.f, 0.f, 0.f, 0.f};

  short8 aX0, aX1, aX2, aX3, aY0, aY1, aY2, aY3;
  float fX[16], fY[16];

#define GLOAD_A(step, a0, a1, a2, a3) do {                                    \
    a0 = a_base0[(step) * 4];  /* 32 bf16 = 4 short8 per step */              \
    a1 = a_base1[(step) * 4];                                                 \
    a2 = a_base2[(step) * 4];                                                 \
    a3 = a_base3[(step) * 4];                                                 \
  } while (0)
#define GLOAD_B(step, f) do {                                                 \
    const float* _b = b_base + (size_t)(step) * 32 * H_;                      \
    _Pragma("unroll")                                                         \
    for (int i = 0; i < 8; ++i) {                                             \
      f[i] = _b[i * H_];                                                      \
      f[8 + i] = _b[i * H_ + 16];                                             \
    }                                                                         \
  } while (0)
#define DO_MFMA(a0, a1, a2, a3, f) do {                                       \
    union { unsigned u[4]; short8 s; } _b0, _b1;                              \
    _Pragma("unroll")                                                         \
    for (int i = 0; i < 4; ++i) {                                             \
      _b0.u[i] = pk2(f[2 * i], f[2 * i + 1]);                                 \
      _b1.u[i] = pk2(f[8 + 2 * i], f[8 + 2 * i + 1]);                         \
    }                                                                         \
    acc[0][0] = __builtin_amdgcn_mfma_f32_16x16x32_bf16(a0, _b0.s, acc[0][0], 0, 0, 0); \
    acc[1][0] = __builtin_amdgcn_mfma_f32_16x16x32_bf16(a1, _b0.s, acc[1][0], 0, 0, 0); \
    acc[2][0] = __builtin_amdgcn_mfma_f32_16x16x32_bf16(a2, _b0.s, acc[2][0], 0, 0, 0); \
    acc[3][0] = __builtin_amdgcn_mfma_f32_16x16x32_bf16(a3, _b0.s, acc[3][0], 0, 0, 0); \
    acc[0][1] = __builtin_amdgcn_mfma_f32_16x16x32_bf16(a0, _b1.s, acc[0][1], 0, 0, 0); \
    acc[1][1] = __builtin_amdgcn_mfma_f32_16x16x32_bf16(a1, _b1.s, acc[1][1], 0, 0, 0); \
    acc[2][1] = __builtin_amdgcn_mfma_f32_16x16x32_bf16(a2, _b1.s, acc[2][1], 0, 0, 0); \
    acc[3][1] = __builtin_amdgcn_mfma_f32_16x16x32_bf16(a3, _b1.s, acc[3][1], 0, 0, 0); \
  } while (0)

  GLOAD_A(0, aX0, aX1, aX2, aX3);
  GLOAD_B(0, fX);
#pragma unroll
  for (int s2 = 0; s2 < FC1_KSTEPS; s2 += 2) {
    GLOAD_A(s2 + 1, aY0, aY1, aY2, aY3);
    GLOAD_B(s2 + 1, fY);
    DO_MFMA(aX0, aX1, aX2, aX3, fX);
    if (s2 + 2 < FC1_KSTEPS) {
      GLOAD_A(s2 + 2, aX0, aX1, aX2, aX3);
      GLOAD_B(s2 + 2, fX);
    }
    DO_MFMA(aY0, aY1, aY2, aY3, fY);
  }

#undef GLOAD_A
#undef GLOAD_B
#undef DO_MFMA

  // D layout: col = lane&15 (=r), row = g*4 + q
  float* p = partial + (size_t)s * (256 * 512);
#pragma unroll
  for (int fm = 0; fm < 4; ++fm)
#pragma unroll
    for (int fn = 0; fn < 2; ++fn)
#pragma unroll
      for (int q = 0; q < 4; ++q) {
        int m = wm + fm * 16 + g * 4 + q;
        int n = n0 + wn + fn * 16 + r;
        p[m * 512 + n] = acc[fm][fn][q];
      }
}

// ---------------- K4: reduce partials + bias + relu + fc2 + softmax ----------------
__global__ __launch_bounds__(512) void k_head(
    const float* __restrict__ partial, const float* __restrict__ bf1,
    const float* __restrict__ Wf2, const float* __restrict__ bf2,
    float* __restrict__ out) {
  __shared__ float red[8][12];
  int b = blockIdx.x;
  int t = threadIdx.x;
  float v = bf1[t];
#pragma unroll
  for (int s = 0; s < S_SPLIT; ++s)
    v += partial[(size_t)s * (256 * 512) + b * 512 + t];
  v = fmaxf(v, 0.f);
  float pacc[10];
#pragma unroll
  for (int j = 0; j < 10; ++j) pacc[j] = v * Wf2[t * 10 + j];
#pragma unroll
  for (int j = 0; j < 10; ++j)
#pragma unroll
    for (int d = 32; d > 0; d >>= 1)
      pacc[j] += __shfl_down(pacc[j], d);
  int wv = t >> 6, ln = t & 63;
  if (ln == 0) {
#pragma unroll
    for (int j = 0; j < 10; ++j) red[wv][j] = pacc[j];
  }
  __syncthreads();
  if (t == 0) {
    float lg[10];
    float m = -1e30f;
#pragma unroll
    for (int j = 0; j < 10; ++j) {
      float z = bf2[j];
#pragma unroll
      for (int wq = 0; wq < 8; ++wq) z += red[wq][j];
      lg[j] = z;
      m = fmaxf(m, z);
    }
    float sum = 0.f;
#pragma unroll
    for (int j = 0; j < 10; ++j) { lg[j] = __expf(lg[j] - m); sum += lg[j]; }
    float inv = 1.f / sum;
#pragma unroll
    for (int j = 0; j < 10; ++j) out[b * 10 + j] = lg[j] * inv;
  }
}

extern "C" void kernel_launch(void* const* d_in, const int* in_sizes, int n_in,
                              void* d_out, int out_size, void* d_ws, size_t ws_size,
                              hipStream_t stream) {
  const float* x    = (const float*)d_in[0];
  const int*   erow = (const int*)d_in[1];
  const int*   ecol = (const int*)d_in[2];
  const float* ev   = (const float*)d_in[3];
  const float* W1   = (const float*)d_in[4];
  const float* b1   = (const float*)d_in[5];
  const float* W2   = (const float*)d_in[6];
  const float* b2   = (const float*)d_in[7];
  const float* Wf1  = (const float*)d_in[8];
  const float* bf1  = (const float*)d_in[9];
  const float* Wf2  = (const float*)d_in[10];
  const float* bf2  = (const float*)d_in[11];
  float* out = (float*)d_out;

  const size_t partial_bytes = (size_t)S_SPLIT * 256 * 512 * 4;   // 14,680,064
  const size_t flat_bytes    = (size_t)B_ * NK * 2;               // 12,845,056

  // ws layout:
  //   [0, 0.80M)         xT f32             (dead after gc1)
  //   [0.80M, 13.65M)    h1 bf16 node-major (dead after gc2)
  //   [0, 14.68M)        partial            (fc1 writes after h1/xT dead)
  //   [14.68M, 27.53M)   flat bf16
  //   tail               CSR (row_ptr, col_s, val_s)
  char* ws = (char*)d_ws;
  float* partial = (float*)ws;
  float* xT = (float*)ws;
  __hip_bfloat16* h1 = (__hip_bfloat16*)(ws + 802816);
  __hip_bfloat16* flat = (__hip_bfloat16*)(ws + partial_bytes);
  char* tail = ws + partial_bytes + flat_bytes;
  int*   row_ptr = (int*)tail;
  int*   col_s   = (int*)(tail + 3152);
  float* val_s   = (float*)(tail + 3152 + E_ * 4);

  hipLaunchKernelGGL(k_prep, dim3(1 + 25 * 8), dim3(1024), 0, stream,
                     erow, ecol, ev, x, row_ptr, col_s, val_s, xT);
  hipLaunchKernelGGL(k_gc1, dim3(N_), dim3(256), 0, stream,
                     xT, row_ptr, col_s, val_s, W1, b1, h1);
  hipLaunchKernelGGL(k_gc2, dim3(N_), dim3(256), 0, stream,
                     h1, row_ptr, col_s, val_s, W2, b2, flat);
  hipLaunchKernelGGL(k_fc1, dim3(S_SPLIT * 8), dim3(512), 0, stream,
                     flat, Wf1, partial);
  hipLaunchKernelGGL(k_head, dim3(B_), dim3(512), 0, stream,
                     partial, bf1, Wf2, bf2, out);
}